// Round 4
// baseline (19431.367 us; speedup 1.0000x reference)
//
#include <hip/hip_runtime.h>

typedef unsigned short u16;
typedef unsigned long long u64;
typedef __attribute__((ext_vector_type(8))) short short8;
typedef __attribute__((ext_vector_type(4))) float f32x4;

#define DEVINL __device__ __forceinline__

constexpr int Nb = 64;     // batch
constexpr int Tt = 1024;   // time
constexpr int Dd = 1024;   // input dim
constexpr int Hh = 1024;   // hidden
constexpr int NWG = 256;   // workgroups (== CUs)
constexpr int TPB = 256;   // threads per wg (4 waves)
constexpr int TWG = 128;   // wgs per team
constexpr int MS  = 32;    // samples per team

struct Flag { unsigned v; unsigned pad[31]; };  // one 128B line each

DEVINL u16 f2b(float f) {
  union { float f; unsigned u; } v; v.f = f;
  unsigned r = (v.u + 0x7fffu + ((v.u >> 16) & 1u)) >> 16;
  return (u16)r;
}
DEVINL float sigm(float x) { return 1.f / (1.f + __expf(-x)); }
DEVINL float tanhfast(float x) { float e = __expf(2.f * x); return 1.f - 2.f / (e + 1.f); }

// Step-boundary fences (canonical fence-fence sync):
//   producer: normal h stores -> fence_rel (vmcnt drain + buffer_wbl2) -> relaxed flag store
//   consumer: relaxed flag poll -> fence_acq (buffer_inv) -> normal cached h loads
// No cache-maintenance inside poll loops; h data rides the per-XCD L2.
DEVINL void fence_acq() { __builtin_amdgcn_fence(__ATOMIC_ACQUIRE, "agent"); }
DEVINL void fence_rel() { __builtin_amdgcn_fence(__ATOMIC_RELEASE, "agent"); }

__global__ void cvt_x_kernel(const float* __restrict__ x, u16* __restrict__ xb) {
  size_t i = ((size_t)blockIdx.x * TPB + threadIdx.x) * 8;
  float4 a = *reinterpret_cast<const float4*>(x + i);
  float4 b = *reinterpret_cast<const float4*>(x + i + 4);
  short8 r;
  r[0] = (short)f2b(a.x); r[1] = (short)f2b(a.y);
  r[2] = (short)f2b(a.z); r[3] = (short)f2b(a.w);
  r[4] = (short)f2b(b.x); r[5] = (short)f2b(b.y);
  r[6] = (short)f2b(b.z); r[7] = (short)f2b(b.w);
  *reinterpret_cast<short8*>(xb + i) = r;
}

// 2 independent teams x 128 wgs; team owns 32 samples, wg owns 8 h-cols.
// [Wh;Wx] slice [32][2048] bf16 LDS-resident (XOR-swizzled). All 4 waves
// split K 4-ways: per step each wave does a 256-wide x slice (pre-poll),
// polls its own 32 producer flags, acquire-fence, then a 256-wide h slice
// with cached loads. Epilogue reduces 4 psums, computes gates, stores h
// (normal) -> release fence -> flag (relaxed SC1). out goes SC1.
template<bool XBF16>
__global__ __launch_bounds__(TPB, 1) void lstm_team(
    const float* __restrict__ x, const u16* __restrict__ xb,
    const float* __restrict__ h0, const float* __restrict__ Wx,
    const float* __restrict__ Wh, const float* __restrict__ bias,
    float* __restrict__ out, u16* __restrict__ hbase,
    Flag* __restrict__ arr)
{
  __shared__ u16 Bt[32][2048];       // 128 KiB, [c][k ^ ((c&7)<<3)]
  __shared__ float ex[4][32][36];    // 18 KiB partial-sum exchange
  __shared__ u16 hstage[32][8];      // h repack for u64 stores

  const int g   = blockIdx.x;
  const int tid = threadIdx.x;
  const int w   = tid >> 6;
  const int l   = tid & 63;

  const int team = ((g & 7) < 4) ? 0 : 1;
  const int r    = (g >> 3) * 4 + (g & 3);  // rank in team, 0..127
  const int n0   = team * MS;
  const int jc0  = r * 8;                   // this wg's 8 h-columns

  Flag* tArr = arr + team * TWG;
  u16*  hb0  = hbase + (size_t)team * (2 * MS * Hh);

  // ---- one-time: [Wh;Wx] column slice -> LDS bf16, swizzled ----
  for (int idx = tid; idx < 32 * 2048; idx += TPB) {
    int k = idx >> 5;
    int c = idx & 31;
    int pc = (c >> 3) * 1024 + jc0 + (c & 7);
    float v = (k < 1024) ? Wh[(size_t)k * 4096 + pc]
                         : Wx[(size_t)(k - 1024) * 4096 + pc];
    Bt[c][k ^ ((c & 7) << 3)] = f2b(v);
  }

  // ---- one-time: h0 -> ping slot 0 (normal stores + release + flag) ----
  if (tid < 64) {
    int v0 = r * 256 + tid * 4;  // team-flat h index, this wg's 256-slice
    const float* hp = h0 + (size_t)n0 * Hh + v0;
    u64 pk = (u64)f2b(hp[0]) | ((u64)f2b(hp[1]) << 16) |
             ((u64)f2b(hp[2]) << 32) | ((u64)f2b(hp[3]) << 48);
    *reinterpret_cast<u64*>(hb0 + v0) = pk;
    fence_rel();
    if (tid == 0)
      __hip_atomic_store(&tArr[r].v, 1u, __ATOMIC_RELAXED, __HIP_MEMORY_SCOPE_AGENT);
  }
  __syncthreads();  // Bt ready

  // epilogue roles: thread -> (nE = tid>>3, jj = tid&7)
  const int jj = tid & 7;
  const int nE = tid >> 3;
  const float bI = bias[0 * 1024 + jc0 + jj];
  const float bF = bias[1 * 1024 + jc0 + jj];
  const float bO = bias[2 * 1024 + jc0 + jj];
  const float bG = bias[3 * 1024 + jc0 + jj];
  float c_reg = 0.f;

  // MFMA lane roles; each wave owns K-slice [256w, 256w+256) of h AND of x
  const int arow = l & 15;
  const int kg   = (l >> 4) * 8;
  const int kb   = w * 256;
  const int sw   = (l & 7) << 3;
  const u16* bp0 = &Bt[l & 15][0];
  const u16* bp1 = &Bt[16 | (l & 15)][0];

  for (int t = 0; t < Tt; ++t) {
    const u16* hb  = hb0 + (t & 1) * (MS * Hh);
    u16*       hbn = hb0 + ((t + 1) & 1) * (MS * Hh);

    f32x4 a00 = {0.f,0.f,0.f,0.f}, a01 = {0.f,0.f,0.f,0.f};
    f32x4 a10 = {0.f,0.f,0.f,0.f}, a11 = {0.f,0.f,0.f,0.f};

    // ---- phase A: x contribution (no h dependency, hides the flag wait) ----
    {
      const int d0 = kb + kg;
      if constexpr (XBF16) {
        const u16* ap0 = xb + ((size_t)(n0 + arow)      * Tt + t) * Dd + d0;
        const u16* ap1 = xb + ((size_t)(n0 + 16 + arow) * Tt + t) * Dd + d0;
        #pragma unroll
        for (int kk = 0; kk < 256; kk += 32) {
          short8 av0 = *reinterpret_cast<const short8*>(ap0 + kk);
          short8 av1 = *reinterpret_cast<const short8*>(ap1 + kk);
          int ka = (1024 + kb + kg + kk) ^ sw;
          short8 bv0 = *reinterpret_cast<const short8*>(bp0 + ka);
          short8 bv1 = *reinterpret_cast<const short8*>(bp1 + ka);
          a00 = __builtin_amdgcn_mfma_f32_16x16x32_bf16(av0, bv0, a00, 0, 0, 0);
          a01 = __builtin_amdgcn_mfma_f32_16x16x32_bf16(av0, bv1, a01, 0, 0, 0);
          a10 = __builtin_amdgcn_mfma_f32_16x16x32_bf16(av1, bv0, a10, 0, 0, 0);
          a11 = __builtin_amdgcn_mfma_f32_16x16x32_bf16(av1, bv1, a11, 0, 0, 0);
        }
      } else {
        const float* ap0 = x + ((size_t)(n0 + arow)      * Tt + t) * Dd + d0;
        const float* ap1 = x + ((size_t)(n0 + 16 + arow) * Tt + t) * Dd + d0;
        #pragma unroll
        for (int kk = 0; kk < 256; kk += 32) {
          float4 xa = *reinterpret_cast<const float4*>(ap0 + kk);
          float4 xc = *reinterpret_cast<const float4*>(ap0 + kk + 4);
          float4 ya = *reinterpret_cast<const float4*>(ap1 + kk);
          float4 yc = *reinterpret_cast<const float4*>(ap1 + kk + 4);
          short8 av0, av1;
          av0[0]=(short)f2b(xa.x); av0[1]=(short)f2b(xa.y);
          av0[2]=(short)f2b(xa.z); av0[3]=(short)f2b(xa.w);
          av0[4]=(short)f2b(xc.x); av0[5]=(short)f2b(xc.y);
          av0[6]=(short)f2b(xc.z); av0[7]=(short)f2b(xc.w);
          av1[0]=(short)f2b(ya.x); av1[1]=(short)f2b(ya.y);
          av1[2]=(short)f2b(ya.z); av1[3]=(short)f2b(ya.w);
          av1[4]=(short)f2b(yc.x); av1[5]=(short)f2b(yc.y);
          av1[6]=(short)f2b(yc.z); av1[7]=(short)f2b(yc.w);
          int ka = (1024 + kb + kg + kk) ^ sw;
          short8 bv0 = *reinterpret_cast<const short8*>(bp0 + ka);
          short8 bv1 = *reinterpret_cast<const short8*>(bp1 + ka);
          a00 = __builtin_amdgcn_mfma_f32_16x16x32_bf16(av0, bv0, a00, 0, 0, 0);
          a01 = __builtin_amdgcn_mfma_f32_16x16x32_bf16(av0, bv1, a01, 0, 0, 0);
          a10 = __builtin_amdgcn_mfma_f32_16x16x32_bf16(av1, bv0, a10, 0, 0, 0);
          a11 = __builtin_amdgcn_mfma_f32_16x16x32_bf16(av1, bv1, a11, 0, 0, 0);
        }
      }
    }

    // ---- phase B: poll this wave's 32 producer flags (relaxed, no fence) ----
    if (l < 32) {
      const unsigned ep = (unsigned)(t + 1);
      while (__hip_atomic_load(&tArr[32 * w + l].v, __ATOMIC_RELAXED,
                               __HIP_MEMORY_SCOPE_AGENT) < ep)
        __builtin_amdgcn_s_sleep(1);
    }
    fence_acq();  // buffer_inv: all subsequent cached h loads see fresh data

    // ---- phase C: h contribution, normal cached loads (L2-shared) ----
    {
      const u16* ap = hb + (size_t)arow * Hh + kb + kg;
      #pragma unroll
      for (int kk = 0; kk < 256; kk += 32) {
        short8 av0 = *reinterpret_cast<const short8*>(ap + kk);
        short8 av1 = *reinterpret_cast<const short8*>(ap + 16 * Hh + kk);
        int ka = (kb + kg + kk) ^ sw;
        short8 bv0 = *reinterpret_cast<const short8*>(bp0 + ka);
        short8 bv1 = *reinterpret_cast<const short8*>(bp1 + ka);
        a00 = __builtin_amdgcn_mfma_f32_16x16x32_bf16(av0, bv0, a00, 0, 0, 0);
        a01 = __builtin_amdgcn_mfma_f32_16x16x32_bf16(av0, bv1, a01, 0, 0, 0);
        a10 = __builtin_amdgcn_mfma_f32_16x16x32_bf16(av1, bv0, a10, 0, 0, 0);
        a11 = __builtin_amdgcn_mfma_f32_16x16x32_bf16(av1, bv1, a11, 0, 0, 0);
      }
    }

    // ---- phase D: partial sums -> LDS ----
    #pragma unroll
    for (int q = 0; q < 4; ++q) {
      ex[w][ 0 + (l >> 4) * 4 + q][ 0 + (l & 15)] = a00[q];
      ex[w][ 0 + (l >> 4) * 4 + q][16 + (l & 15)] = a01[q];
      ex[w][16 + (l >> 4) * 4 + q][ 0 + (l & 15)] = a10[q];
      ex[w][16 + (l >> 4) * 4 + q][16 + (l & 15)] = a11[q];
    }
    __syncthreads();

    // ---- phase E: gates, state update ----
    float pI = bI, pF = bF, pO = bO, pG = bG;
    #pragma unroll
    for (int wv = 0; wv < 4; ++wv) {
      pI += ex[wv][nE][ 0 + jj];
      pF += ex[wv][nE][ 8 + jj];
      pO += ex[wv][nE][16 + jj];
      pG += ex[wv][nE][24 + jj];
    }
    const float ig = sigm(pI), fg = sigm(pF), og = sigm(pO);
    const float gg = tanhfast(pG);
    c_reg = fg * c_reg + ig * gg;
    const float hv = og * tanhfast(c_reg);

    hstage[nE][jj] = f2b(hv);
    __syncthreads();

    // wave0: normal h stores (local L2) -> release fence (wbl2, tiny dirty
    // set) -> relaxed flag store. out-stores are SC1 so they never enter
    // the fenced dirty set.
    if (tid < 64) {
      int n  = tid >> 1;
      int jc = (tid & 1) * 4;
      *reinterpret_cast<u64*>(hbn + n * Hh + jc0 + jc) =
          *reinterpret_cast<const u64*>(&hstage[n][jc]);
      fence_rel();
      if (tid == 0 && t + 1 < Tt)
        __hip_atomic_store(&tArr[r].v, (unsigned)(t + 2),
                           __ATOMIC_RELAXED, __HIP_MEMORY_SCOPE_AGENT);
    }
    {
      union { float f; unsigned u; } cv; cv.f = hv;
      __hip_atomic_store(
          (unsigned*)&out[((size_t)(n0 + nE) * Tt + t) * Hh + jc0 + jj],
          cv.u, __ATOMIC_RELAXED, __HIP_MEMORY_SCOPE_AGENT);
    }
  }
}

extern "C" void kernel_launch(void* const* d_in, const int* in_sizes, int n_in,
                              void* d_out, int out_size, void* d_ws, size_t ws_size,
                              hipStream_t stream) {
  const float* x    = (const float*)d_in[0];
  const float* h0   = (const float*)d_in[1];
  const float* Wx   = (const float*)d_in[2];
  const float* Wh   = (const float*)d_in[3];
  const float* bias = (const float*)d_in[4];
  float* out = (float*)d_out;

  char* wsb = (char*)d_ws;
  Flag* arr   = (Flag*)wsb;                        // 2*128 lines = 32 KiB
  u16*  hbase = (u16*)(wsb + 65536);               // 2 teams x 2 x 32 x 1024 bf16
  const size_t xb_off = (size_t)1 << 20;
  const size_t xb_bytes = (size_t)Nb * Tt * Dd * 2;
  u16* xb = (u16*)(wsb + xb_off);

  hipMemsetAsync(wsb, 0, 40960, stream);           // clear flags each launch

  const bool use_xb = ws_size >= xb_off + xb_bytes;
  void* args[] = {(void*)&x, (void*)&xb, (void*)&h0, (void*)&Wx, (void*)&Wh,
                  (void*)&bias, (void*)&out, (void*)&hbase, (void*)&arr};
  if (use_xb) {
    cvt_x_kernel<<<dim3((Nb * Tt * Dd) / (8 * TPB)), dim3(TPB), 0, stream>>>(x, xb);
    hipLaunchCooperativeKernel((const void*)lstm_team<true>,
                               dim3(NWG), dim3(TPB), args, 0, stream);
  } else {
    hipLaunchCooperativeKernel((const void*)lstm_team<false>,
                               dim3(NWG), dim3(TPB), args, 0, stream);
  }
}

// Round 5
// 8507.500 us; speedup vs baseline: 2.2840x; 2.2840x over previous
//
#include <hip/hip_runtime.h>

typedef unsigned short u16;
typedef unsigned long long u64;
typedef __attribute__((ext_vector_type(8))) short short8;
typedef __attribute__((ext_vector_type(4))) float f32x4;

#define DEVINL __device__ __forceinline__

constexpr int Nb = 64;     // batch
constexpr int Tt = 1024;   // time
constexpr int Dd = 1024;   // input dim
constexpr int Hh = 1024;   // hidden
constexpr int NWG = 256;   // workgroups (== CUs)
constexpr int TPB = 256;   // threads per wg (4 waves)
constexpr int TWG = 128;   // wgs per team
constexpr int MS  = 32;    // samples per team

struct Flag { unsigned v; unsigned pad[31]; };  // one 128B line each

DEVINL u16 f2b(float f) {
  union { float f; unsigned u; } v; v.f = f;
  unsigned r = (v.u + 0x7fffu + ((v.u >> 16) & 1u)) >> 16;
  return (u16)r;
}
DEVINL float sigm(float x) { return 1.f / (1.f + __expf(-x)); }
DEVINL float tanhfast(float x) { float e = __expf(2.f * x); return 1.f - 2.f / (e + 1.f); }

// IC-coherent (SC1) h-fragment load: 2x relaxed u64 agent atomics.
DEVINL short8 ldh16(const u16* p) {
  u64 a = __hip_atomic_load((const u64*)p,       __ATOMIC_RELAXED, __HIP_MEMORY_SCOPE_AGENT);
  u64 b = __hip_atomic_load((const u64*)(p + 4), __ATOMIC_RELAXED, __HIP_MEMORY_SCOPE_AGENT);
  union { u64 q[2]; short8 v; } u;
  u.q[0] = a; u.q[1] = b;
  return u.v;
}

// Raw LDS barrier: writer-side lgkmcnt drain + s_barrier. Does NOT drain
// vmcnt (T4 property) -> global stores/loads stay in flight across it.
DEVINL void bar_w() {
  asm volatile("s_waitcnt lgkmcnt(0)" ::: "memory");
  __builtin_amdgcn_s_barrier();
}

__global__ void cvt_x_kernel(const float* __restrict__ x, u16* __restrict__ xb) {
  size_t i = ((size_t)blockIdx.x * TPB + threadIdx.x) * 8;
  float4 a = *reinterpret_cast<const float4*>(x + i);
  float4 b = *reinterpret_cast<const float4*>(x + i + 4);
  short8 r;
  r[0] = (short)f2b(a.x); r[1] = (short)f2b(a.y);
  r[2] = (short)f2b(a.z); r[3] = (short)f2b(a.w);
  r[4] = (short)f2b(b.x); r[5] = (short)f2b(b.y);
  r[6] = (short)f2b(b.z); r[7] = (short)f2b(b.w);
  *reinterpret_cast<short8*>(xb + i) = r;
}

// 2 independent teams x 128 wgs; team owns 32 samples, wg owns 8 h-cols.
// Weights register-resident per wave (B-fragments loop-invariant). SC1
// protocol for h + flags (no cache maintenance anywhere). Per step:
// x-frag loads -> wave gate on own 32 producer flags -> SC1 h loads issue
// -> x MFMAs (hide h latency) -> h MFMAs -> ex LDS reduce (raw barrier)
// -> gates -> hstage (raw barrier) -> wave0 SC1 h store + vmcnt + flag.
template<bool XBF16>
__global__ __launch_bounds__(TPB, 1) void lstm_team(
    const float* __restrict__ x, const u16* __restrict__ xb,
    const float* __restrict__ h0, const float* __restrict__ Wx,
    const float* __restrict__ Wh, const float* __restrict__ bias,
    float* __restrict__ out, u16* __restrict__ hbase,
    Flag* __restrict__ arr)
{
  __shared__ u16 Bt[32][2048];       // 128 KiB (one-time staging)
  __shared__ float ex[4][32][36];    // 18 KiB partial-sum exchange
  __shared__ u16 hstage[32][8];      // h repack for u64 stores

  const int g   = blockIdx.x;
  const int tid = threadIdx.x;
  const int w   = tid >> 6;
  const int l   = tid & 63;

  const int team = ((g & 7) < 4) ? 0 : 1;
  const int r    = (g >> 3) * 4 + (g & 3);  // rank in team, 0..127
  const int n0   = team * MS;
  const int jc0  = r * 8;                   // this wg's 8 h-columns

  Flag* tArr = arr + team * TWG;
  u16*  hb0  = hbase + (size_t)team * (2 * MS * Hh);

  // ---- one-time: [Wh;Wx] column slice -> LDS bf16, swizzled ----
  for (int idx = tid; idx < 32 * 2048; idx += TPB) {
    int k = idx >> 5;
    int c = idx & 31;
    int pc = (c >> 3) * 1024 + jc0 + (c & 7);
    float v = (k < 1024) ? Wh[(size_t)k * 4096 + pc]
                         : Wx[(size_t)(k - 1024) * 4096 + pc];
    Bt[c][k ^ ((c & 7) << 3)] = f2b(v);
  }

  // ---- one-time: h0 -> ping slot 0 via SC1 stores + flag=1 ----
  if (tid < 64) {
    int v0 = r * 256 + tid * 4;  // team-flat h index
    const float* hp = h0 + (size_t)n0 * Hh + v0;
    u64 pk = (u64)f2b(hp[0]) | ((u64)f2b(hp[1]) << 16) |
             ((u64)f2b(hp[2]) << 32) | ((u64)f2b(hp[3]) << 48);
    __hip_atomic_store((u64*)(hb0 + v0), pk, __ATOMIC_RELAXED, __HIP_MEMORY_SCOPE_AGENT);
    asm volatile("s_waitcnt vmcnt(0)" ::: "memory");
    if (tid == 0)
      __hip_atomic_store(&tArr[r].v, 1u, __ATOMIC_RELAXED, __HIP_MEMORY_SCOPE_AGENT);
  }
  __syncthreads();  // Bt ready (full sync, one-time)

  // epilogue roles
  const int jj = tid & 7;
  const int nE = tid >> 3;
  const float bI = bias[0 * 1024 + jc0 + jj];
  const float bF = bias[1 * 1024 + jc0 + jj];
  const float bO = bias[2 * 1024 + jc0 + jj];
  const float bG = bias[3 * 1024 + jc0 + jj];
  float c_reg = 0.f;

  // MFMA lane roles; wave owns K-slice [256w, 256w+256)
  const int arow = l & 15;
  const int kg   = (l >> 4) * 8;
  const int kb   = w * 256;
  const int sw   = (l & 7) << 3;
  const u16* bp0 = &Bt[l & 15][0];
  const u16* bp1 = &Bt[16 | (l & 15)][0];

  // ---- hoist loop-invariant B-fragments into registers (128 VGPR) ----
  short8 bh0[8], bh1[8], bx0[8], bx1[8];
  #pragma unroll
  for (int i = 0; i < 8; ++i) {
    int ka = (kb + kg + 32 * i) ^ sw;
    bh0[i] = *reinterpret_cast<const short8*>(bp0 + ka);
    bh1[i] = *reinterpret_cast<const short8*>(bp1 + ka);
    int kx = (1024 + kb + kg + 32 * i) ^ sw;
    bx0[i] = *reinterpret_cast<const short8*>(bp0 + kx);
    bx1[i] = *reinterpret_cast<const short8*>(bp1 + kx);
  }

  for (int t = 0; t < Tt; ++t) {
    const u16* hb  = hb0 + (t & 1) * (MS * Hh);
    u16*       hbn = hb0 + ((t + 1) & 1) * (MS * Hh);

    // ---- x-fragment loads BEFORE the gate (latency hides under wait) ----
    short8 xv0[8], xv1[8];
    if constexpr (XBF16) {
      const u16* xr0 = xb + ((size_t)(n0 + arow)      * Tt + t) * Dd + kb + kg;
      const u16* xr1 = xb + ((size_t)(n0 + 16 + arow) * Tt + t) * Dd + kb + kg;
      #pragma unroll
      for (int i = 0; i < 8; ++i) {
        xv0[i] = *reinterpret_cast<const short8*>(xr0 + 32 * i);
        xv1[i] = *reinterpret_cast<const short8*>(xr1 + 32 * i);
      }
    } else {
      const float* xr0 = x + ((size_t)(n0 + arow)      * Tt + t) * Dd + kb + kg;
      const float* xr1 = x + ((size_t)(n0 + 16 + arow) * Tt + t) * Dd + kb + kg;
      #pragma unroll
      for (int i = 0; i < 8; ++i) {
        float4 a0 = *reinterpret_cast<const float4*>(xr0 + 32 * i);
        float4 a1 = *reinterpret_cast<const float4*>(xr0 + 32 * i + 4);
        float4 c0 = *reinterpret_cast<const float4*>(xr1 + 32 * i);
        float4 c1 = *reinterpret_cast<const float4*>(xr1 + 32 * i + 4);
        short8 v0, v1;
        v0[0]=(short)f2b(a0.x); v0[1]=(short)f2b(a0.y);
        v0[2]=(short)f2b(a0.z); v0[3]=(short)f2b(a0.w);
        v0[4]=(short)f2b(a1.x); v0[5]=(short)f2b(a1.y);
        v0[6]=(short)f2b(a1.z); v0[7]=(short)f2b(a1.w);
        v1[0]=(short)f2b(c0.x); v1[1]=(short)f2b(c0.y);
        v1[2]=(short)f2b(c0.z); v1[3]=(short)f2b(c0.w);
        v1[4]=(short)f2b(c1.x); v1[5]=(short)f2b(c1.y);
        v1[6]=(short)f2b(c1.z); v1[7]=(short)f2b(c1.w);
        xv0[i] = v0; xv1[i] = v1;
      }
    }

    // ---- wave-uniform gate: this wave's 32 producers at epoch >= t+1 ----
    {
      const unsigned ep = (unsigned)(t + 1);
      bool rdy;
      do {
        unsigned f = 0xFFFFFFFFu;
        if (l < 32)
          f = __hip_atomic_load(&tArr[32 * w + l].v, __ATOMIC_RELAXED,
                                __HIP_MEMORY_SCOPE_AGENT);
        rdy = (bool)__all(f >= ep);
        if (!rdy) __builtin_amdgcn_s_sleep(1);
      } while (!rdy);
    }

    // ---- issue SC1 h loads (in flight during x-MFMAs) ----
    short8 hv0[8], hv1[8];
    {
      const u16* hr = hb + (size_t)arow * Hh + kb + kg;
      #pragma unroll
      for (int i = 0; i < 8; ++i) {
        hv0[i] = ldh16(hr + 32 * i);
        hv1[i] = ldh16(hr + 16 * Hh + 32 * i);
      }
    }

    f32x4 a00 = {0.f,0.f,0.f,0.f}, a01 = {0.f,0.f,0.f,0.f};
    f32x4 a10 = {0.f,0.f,0.f,0.f}, a11 = {0.f,0.f,0.f,0.f};

    // ---- x MFMAs (data already resident) ----
    #pragma unroll
    for (int i = 0; i < 8; ++i) {
      a00 = __builtin_amdgcn_mfma_f32_16x16x32_bf16(xv0[i], bx0[i], a00, 0, 0, 0);
      a01 = __builtin_amdgcn_mfma_f32_16x16x32_bf16(xv0[i], bx1[i], a01, 0, 0, 0);
      a10 = __builtin_amdgcn_mfma_f32_16x16x32_bf16(xv1[i], bx0[i], a10, 0, 0, 0);
      a11 = __builtin_amdgcn_mfma_f32_16x16x32_bf16(xv1[i], bx1[i], a11, 0, 0, 0);
    }
    // ---- h MFMAs ----
    #pragma unroll
    for (int i = 0; i < 8; ++i) {
      a00 = __builtin_amdgcn_mfma_f32_16x16x32_bf16(hv0[i], bh0[i], a00, 0, 0, 0);
      a01 = __builtin_amdgcn_mfma_f32_16x16x32_bf16(hv0[i], bh1[i], a01, 0, 0, 0);
      a10 = __builtin_amdgcn_mfma_f32_16x16x32_bf16(hv1[i], bh0[i], a10, 0, 0, 0);
      a11 = __builtin_amdgcn_mfma_f32_16x16x32_bf16(hv1[i], bh1[i], a11, 0, 0, 0);
    }

    // ---- partial sums -> LDS ----
    #pragma unroll
    for (int q = 0; q < 4; ++q) {
      ex[w][ 0 + (l >> 4) * 4 + q][ 0 + (l & 15)] = a00[q];
      ex[w][ 0 + (l >> 4) * 4 + q][16 + (l & 15)] = a01[q];
      ex[w][16 + (l >> 4) * 4 + q][ 0 + (l & 15)] = a10[q];
      ex[w][16 + (l >> 4) * 4 + q][16 + (l & 15)] = a11[q];
    }
    bar_w();  // SYNC1 (no vmcnt drain)

    // ---- gates, state update ----
    float pI = bI, pF = bF, pO = bO, pG = bG;
    #pragma unroll
    for (int wv = 0; wv < 4; ++wv) {
      pI += ex[wv][nE][ 0 + jj];
      pF += ex[wv][nE][ 8 + jj];
      pO += ex[wv][nE][16 + jj];
      pG += ex[wv][nE][24 + jj];
    }
    const float ig = sigm(pI), fg = sigm(pF), og = sigm(pO);
    const float gg = tanhfast(pG);
    c_reg = fg * c_reg + ig * gg;
    const float hv = og * tanhfast(c_reg);

    hstage[nE][jj] = f2b(hv);
    bar_w();  // SYNC2 (no vmcnt drain)

    // wave0: SC1 h store -> ack -> flag. Everything else after.
    if (tid < 64) {
      int n  = tid >> 1;
      int jc = (tid & 1) * 4;
      u64 pk = *reinterpret_cast<const u64*>(&hstage[n][jc]);
      __hip_atomic_store((u64*)(hbn + n * Hh + jc0 + jc), pk,
                         __ATOMIC_RELAXED, __HIP_MEMORY_SCOPE_AGENT);
      asm volatile("s_waitcnt vmcnt(0)" ::: "memory");
      if (tid == 0 && t + 1 < Tt)
        __hip_atomic_store(&tArr[r].v, (unsigned)(t + 2),
                           __ATOMIC_RELAXED, __HIP_MEMORY_SCOPE_AGENT);
    }
    out[((size_t)(n0 + nE) * Tt + t) * Hh + jc0 + jj] = hv;
  }
}

extern "C" void kernel_launch(void* const* d_in, const int* in_sizes, int n_in,
                              void* d_out, int out_size, void* d_ws, size_t ws_size,
                              hipStream_t stream) {
  const float* x    = (const float*)d_in[0];
  const float* h0   = (const float*)d_in[1];
  const float* Wx   = (const float*)d_in[2];
  const float* Wh   = (const float*)d_in[3];
  const float* bias = (const float*)d_in[4];
  float* out = (float*)d_out;

  char* wsb = (char*)d_ws;
  Flag* arr   = (Flag*)wsb;                        // 2*128 lines = 32 KiB
  u16*  hbase = (u16*)(wsb + 65536);               // 2 teams x 2 x 32 x 1024 bf16
  const size_t xb_off = (size_t)1 << 20;
  const size_t xb_bytes = (size_t)Nb * Tt * Dd * 2;
  u16* xb = (u16*)(wsb + xb_off);

  hipMemsetAsync(wsb, 0, 40960, stream);           // clear flags each launch

  const bool use_xb = ws_size >= xb_off + xb_bytes;
  void* args[] = {(void*)&x, (void*)&xb, (void*)&h0, (void*)&Wx, (void*)&Wh,
                  (void*)&bias, (void*)&out, (void*)&hbase, (void*)&arr};
  if (use_xb) {
    cvt_x_kernel<<<dim3((Nb * Tt * Dd) / (8 * TPB)), dim3(TPB), 0, stream>>>(x, xb);
    hipLaunchCooperativeKernel((const void*)lstm_team<true>,
                               dim3(NWG), dim3(TPB), args, 0, stream);
  } else {
    hipLaunchCooperativeKernel((const void*)lstm_team<false>,
                               dim3(NWG), dim3(TPB), args, 0, stream);
  }
}

// Round 7
// 8425.446 us; speedup vs baseline: 2.3063x; 1.0097x over previous
//
#include <hip/hip_runtime.h>

typedef unsigned short u16;
typedef unsigned long long u64;
typedef __attribute__((ext_vector_type(8))) short short8;
typedef __attribute__((ext_vector_type(4))) float f32x4;

#define DEVINL __device__ __forceinline__

constexpr int Nb = 64;     // batch
constexpr int Tt = 1024;   // time
constexpr int Dd = 1024;   // input dim
constexpr int Hh = 1024;   // hidden
constexpr int NWG = 256;   // workgroups (== CUs)
constexpr int TPB = 256;   // threads per wg (4 waves)
constexpr int TWG = 128;   // wgs per team
constexpr int MS  = 32;    // samples per team

DEVINL u16 f2b(float f) {
  union { float f; unsigned u; } v; v.f = f;
  unsigned r = (v.u + 0x7fffu + ((v.u >> 16) & 1u)) >> 16;
  return (u16)r;
}
DEVINL float sigm(float x) { return 1.f / (1.f + __expf(-x)); }
DEVINL float tanhfast(float x) { float e = __expf(2.f * x); return 1.f - 2.f / (e + 1.f); }

// IC-coherent (SC1) h-fragment load: 2x relaxed u64 agent atomics.
DEVINL short8 ldh16(const u16* p) {
  u64 a = __hip_atomic_load((const u64*)p,       __ATOMIC_RELAXED, __HIP_MEMORY_SCOPE_AGENT);
  u64 b = __hip_atomic_load((const u64*)(p + 4), __ATOMIC_RELAXED, __HIP_MEMORY_SCOPE_AGENT);
  union { u64 q[2]; short8 v; } u;
  u.q[0] = a; u.q[1] = b;
  return u.v;
}

// Raw LDS barrier: writer-side lgkmcnt drain + s_barrier. Does NOT drain
// vmcnt -> global stores/loads stay in flight across it.
DEVINL void bar_w() {
  asm volatile("s_waitcnt lgkmcnt(0)" ::: "memory");
  __builtin_amdgcn_s_barrier();
}

__global__ void cvt_x_kernel(const float* __restrict__ x, u16* __restrict__ xb) {
  size_t i = ((size_t)blockIdx.x * TPB + threadIdx.x) * 8;
  float4 a = *reinterpret_cast<const float4*>(x + i);
  float4 b = *reinterpret_cast<const float4*>(x + i + 4);
  short8 r;
  r[0] = (short)f2b(a.x); r[1] = (short)f2b(a.y);
  r[2] = (short)f2b(a.z); r[3] = (short)f2b(a.w);
  r[4] = (short)f2b(b.x); r[5] = (short)f2b(b.y);
  r[6] = (short)f2b(b.z); r[7] = (short)f2b(b.w);
  *reinterpret_cast<short8*>(xb + i) = r;
}

// 2 teams x 128 wgs; team owns 32 samples, wg owns 8 h-cols. SC1 protocol
// for h + flags, flags packed one 128B line per (team, k-group).
// INVARIANT (the r6 bugfix): flag[r] == e guarantees h columns [8r, 8r+8)
// of slot (e-1)&1 hold h_{e-1} for ALL 32 rows — for the INIT (e=1) as well
// as every main-loop step. Consumer wave w polls exactly wgs [32w,32w+32),
// the producers of its K-slice columns [256w, 256w+256).
template<bool XBF16>
__global__ __launch_bounds__(TPB, 1) void lstm_team(
    const float* __restrict__ x, const u16* __restrict__ xb,
    const float* __restrict__ h0, const float* __restrict__ Wx,
    const float* __restrict__ Wh, const float* __restrict__ bias,
    float* __restrict__ out, u16* __restrict__ hbase,
    unsigned* __restrict__ flg)
{
  __shared__ u16 Bt[32][2048];       // 128 KiB (one-time staging)
  __shared__ float ex[4][32][36];    // 18 KiB partial-sum exchange
  __shared__ u16 hstage[32][8];      // h repack for u64 stores
  __shared__ float ostage[8][8];     // wave0's f32 out handoff

  const int g   = blockIdx.x;
  const int tid = threadIdx.x;
  const int w   = tid >> 6;
  const int l   = tid & 63;

  const int team = ((g & 7) < 4) ? 0 : 1;
  const int r    = (g >> 3) * 4 + (g & 3);  // rank in team, 0..127
  const int n0   = team * MS;
  const int jc0  = r * 8;                   // this wg's 8 h-columns

  unsigned* tFlg = flg + team * 4 * 32;     // 4 packed lines of 32 epochs
  u16*      hb0  = hbase + (size_t)team * (2 * MS * Hh);

  // ---- one-time: [Wh;Wx] column slice -> LDS bf16, swizzled ----
  for (int idx = tid; idx < 32 * 2048; idx += TPB) {
    int k = idx >> 5;
    int c = idx & 31;
    int pc = (c >> 3) * 1024 + jc0 + (c & 7);
    float v = (k < 1024) ? Wh[(size_t)k * 4096 + pc]
                         : Wx[(size_t)(k - 1024) * 4096 + pc];
    Bt[c][k ^ ((c & 7) << 3)] = f2b(v);
  }

  // ---- one-time init, SAME ownership as main-loop h-stores:
  //      wg r writes columns [jc0, jc0+8) x rows 0..31 of slot 0 ----
  if (tid < 64) {
    int n  = tid >> 1;
    int jc = (tid & 1) * 4;
    const float* hp = h0 + (size_t)(n0 + n) * Hh + jc0 + jc;
    u64 pk = (u64)f2b(hp[0]) | ((u64)f2b(hp[1]) << 16) |
             ((u64)f2b(hp[2]) << 32) | ((u64)f2b(hp[3]) << 48);
    __hip_atomic_store((u64*)(hb0 + n * Hh + jc0 + jc), pk,
                       __ATOMIC_RELAXED, __HIP_MEMORY_SCOPE_AGENT);
    asm volatile("s_waitcnt vmcnt(0)" ::: "memory");
    if (tid == 0)
      __hip_atomic_store(&tFlg[r], 1u, __ATOMIC_RELAXED, __HIP_MEMORY_SCOPE_AGENT);
  }
  __syncthreads();  // Bt ready (one-time full sync)

  // epilogue roles
  const int jj = tid & 7;
  const int nE = tid >> 3;
  const float bI = bias[0 * 1024 + jc0 + jj];
  const float bF = bias[1 * 1024 + jc0 + jj];
  const float bO = bias[2 * 1024 + jc0 + jj];
  const float bG = bias[3 * 1024 + jc0 + jj];
  float c_reg = 0.f;

  // MFMA lane roles; wave owns K-slice [256w, 256w+256)
  const int arow = l & 15;
  const int kg   = (l >> 4) * 8;
  const int kb   = w * 256;
  const int sw   = (l & 7) << 3;
  const u16* bp0 = &Bt[l & 15][0];
  const u16* bp1 = &Bt[16 | (l & 15)][0];

  // ---- hoist loop-invariant B-fragments ----
  short8 bh0[8], bh1[8], bx0[8], bx1[8];
  #pragma unroll
  for (int i = 0; i < 8; ++i) {
    int ka = (kb + kg + 32 * i) ^ sw;
    bh0[i] = *reinterpret_cast<const short8*>(bp0 + ka);
    bh1[i] = *reinterpret_cast<const short8*>(bp1 + ka);
    int kx = (1024 + kb + kg + 32 * i) ^ sw;
    bx0[i] = *reinterpret_cast<const short8*>(bp0 + kx);
    bx1[i] = *reinterpret_cast<const short8*>(bp1 + kx);
  }

  for (int t = 0; t < Tt; ++t) {
    const u16* hb  = hb0 + (t & 1) * (MS * Hh);
    u16*       hbn = hb0 + ((t + 1) & 1) * (MS * Hh);

    // ---- x-fragment loads BEFORE the gate (latency hides under wait) ----
    short8 xv0[8], xv1[8];
    if constexpr (XBF16) {
      const u16* xr0 = xb + ((size_t)(n0 + arow)      * Tt + t) * Dd + kb + kg;
      const u16* xr1 = xb + ((size_t)(n0 + 16 + arow) * Tt + t) * Dd + kb + kg;
      #pragma unroll
      for (int i = 0; i < 8; ++i) {
        xv0[i] = *reinterpret_cast<const short8*>(xr0 + 32 * i);
        xv1[i] = *reinterpret_cast<const short8*>(xr1 + 32 * i);
      }
    } else {
      const float* xr0 = x + ((size_t)(n0 + arow)      * Tt + t) * Dd + kb + kg;
      const float* xr1 = x + ((size_t)(n0 + 16 + arow) * Tt + t) * Dd + kb + kg;
      #pragma unroll
      for (int i = 0; i < 8; ++i) {
        float4 a0 = *reinterpret_cast<const float4*>(xr0 + 32 * i);
        float4 a1 = *reinterpret_cast<const float4*>(xr0 + 32 * i + 4);
        float4 c0 = *reinterpret_cast<const float4*>(xr1 + 32 * i);
        float4 c1 = *reinterpret_cast<const float4*>(xr1 + 32 * i + 4);
        short8 v0, v1;
        v0[0]=(short)f2b(a0.x); v0[1]=(short)f2b(a0.y);
        v0[2]=(short)f2b(a0.z); v0[3]=(short)f2b(a0.w);
        v0[4]=(short)f2b(a1.x); v0[5]=(short)f2b(a1.y);
        v0[6]=(short)f2b(a1.z); v0[7]=(short)f2b(a1.w);
        v1[0]=(short)f2b(c0.x); v1[1]=(short)f2b(c0.y);
        v1[2]=(short)f2b(c0.z); v1[3]=(short)f2b(c0.w);
        v1[4]=(short)f2b(c1.x); v1[5]=(short)f2b(c1.y);
        v1[6]=(short)f2b(c1.z); v1[7]=(short)f2b(c1.w);
        xv0[i] = v0; xv1[i] = v1;
      }
    }

    // ---- gate: poll this wave's PACKED group line (1 coalesced txn) ----
    {
      const unsigned ep = (unsigned)(t + 1);
      const unsigned* gl = tFlg + w * 32;
      bool rdy;
      do {
        unsigned f = 0xFFFFFFFFu;
        if (l < 32)
          f = __hip_atomic_load(gl + l, __ATOMIC_RELAXED, __HIP_MEMORY_SCOPE_AGENT);
        rdy = (bool)__all(f >= ep);
        if (!rdy) __builtin_amdgcn_s_sleep(1);
      } while (!rdy);
    }

    // ---- issue SC1 h loads (in flight during x-MFMAs) ----
    short8 hv0[8], hv1[8];
    {
      const u16* hr = hb + (size_t)arow * Hh + kb + kg;
      #pragma unroll
      for (int i = 0; i < 8; ++i) {
        hv0[i] = ldh16(hr + 32 * i);
        hv1[i] = ldh16(hr + 16 * Hh + 32 * i);
      }
    }

    f32x4 a00 = {0.f,0.f,0.f,0.f}, a01 = {0.f,0.f,0.f,0.f};
    f32x4 a10 = {0.f,0.f,0.f,0.f}, a11 = {0.f,0.f,0.f,0.f};

    // ---- x MFMAs (data already resident) ----
    #pragma unroll
    for (int i = 0; i < 8; ++i) {
      a00 = __builtin_amdgcn_mfma_f32_16x16x32_bf16(xv0[i], bx0[i], a00, 0, 0, 0);
      a01 = __builtin_amdgcn_mfma_f32_16x16x32_bf16(xv0[i], bx1[i], a01, 0, 0, 0);
      a10 = __builtin_amdgcn_mfma_f32_16x16x32_bf16(xv1[i], bx0[i], a10, 0, 0, 0);
      a11 = __builtin_amdgcn_mfma_f32_16x16x32_bf16(xv1[i], bx1[i], a11, 0, 0, 0);
    }
    // ---- h MFMAs ----
    #pragma unroll
    for (int i = 0; i < 8; ++i) {
      a00 = __builtin_amdgcn_mfma_f32_16x16x32_bf16(hv0[i], bh0[i], a00, 0, 0, 0);
      a01 = __builtin_amdgcn_mfma_f32_16x16x32_bf16(hv0[i], bh1[i], a01, 0, 0, 0);
      a10 = __builtin_amdgcn_mfma_f32_16x16x32_bf16(hv1[i], bh0[i], a10, 0, 0, 0);
      a11 = __builtin_amdgcn_mfma_f32_16x16x32_bf16(hv1[i], bh1[i], a11, 0, 0, 0);
    }

    // ---- partial sums -> LDS ----
    #pragma unroll
    for (int q = 0; q < 4; ++q) {
      ex[w][ 0 + (l >> 4) * 4 + q][ 0 + (l & 15)] = a00[q];
      ex[w][ 0 + (l >> 4) * 4 + q][16 + (l & 15)] = a01[q];
      ex[w][16 + (l >> 4) * 4 + q][ 0 + (l & 15)] = a10[q];
      ex[w][16 + (l >> 4) * 4 + q][16 + (l & 15)] = a11[q];
    }
    bar_w();  // SYNC1 (no vmcnt drain)

    // ---- gates, state update ----
    float pI = bI, pF = bF, pO = bO, pG = bG;
    #pragma unroll
    for (int wv = 0; wv < 4; ++wv) {
      pI += ex[wv][nE][ 0 + jj];
      pF += ex[wv][nE][ 8 + jj];
      pO += ex[wv][nE][16 + jj];
      pG += ex[wv][nE][24 + jj];
    }
    const float ig = sigm(pI), fg = sigm(pF), og = sigm(pO);
    const float gg = tanhfast(pG);
    c_reg = fg * c_reg + ig * gg;
    const float hv = og * tanhfast(c_reg);

    hstage[nE][jj] = f2b(hv);
    if (w == 0) ostage[nE][jj] = hv;   // wave0 rows 0..7 f32 handoff
    bar_w();  // SYNC2 (no vmcnt drain)

    if (tid < 64) {
      // wave0: SC1 h store -> drain (ONLY these stores) -> packed flag
      int n  = tid >> 1;
      int jc = (tid & 1) * 4;
      u64 pk = *reinterpret_cast<const u64*>(&hstage[n][jc]);
      __hip_atomic_store((u64*)(hbn + n * Hh + jc0 + jc), pk,
                         __ATOMIC_RELAXED, __HIP_MEMORY_SCOPE_AGENT);
      asm volatile("s_waitcnt vmcnt(0)" ::: "memory");
      if (tid == 0 && t + 1 < Tt)
        __hip_atomic_store(&tFlg[r], (unsigned)(t + 2),
                           __ATOMIC_RELAXED, __HIP_MEMORY_SCOPE_AGENT);
    } else {
      // waves 1-3: own out values; wave1 also stores wave0's via ostage
      out[((size_t)(n0 + nE) * Tt + t) * Hh + jc0 + jj] = hv;
      if (tid < 128) {
        int n  = (tid - 64) >> 3;
        int jo = (tid - 64) & 7;
        out[((size_t)(n0 + n) * Tt + t) * Hh + jc0 + jo] = ostage[n][jo];
      }
    }
  }
}

extern "C" void kernel_launch(void* const* d_in, const int* in_sizes, int n_in,
                              void* d_out, int out_size, void* d_ws, size_t ws_size,
                              hipStream_t stream) {
  const float* x    = (const float*)d_in[0];
  const float* h0   = (const float*)d_in[1];
  const float* Wx   = (const float*)d_in[2];
  const float* Wh   = (const float*)d_in[3];
  const float* bias = (const float*)d_in[4];
  float* out = (float*)d_out;

  char* wsb = (char*)d_ws;
  unsigned* flg  = (unsigned*)wsb;                 // 2 teams x 4 x 32 u32 = 1 KiB
  u16*     hbase = (u16*)(wsb + 65536);            // 2 teams x 2 x 32 x 1024 bf16
  const size_t xb_off = (size_t)1 << 20;
  const size_t xb_bytes = (size_t)Nb * Tt * Dd * 2;
  u16* xb = (u16*)(wsb + xb_off);

  hipMemsetAsync(wsb, 0, 40960, stream);           // clear flags each launch

  const bool use_xb = ws_size >= xb_off + xb_bytes;
  void* args[] = {(void*)&x, (void*)&xb, (void*)&h0, (void*)&Wx, (void*)&Wh,
                  (void*)&bias, (void*)&out, (void*)&hbase, (void*)&flg};
  if (use_xb) {
    cvt_x_kernel<<<dim3((Nb * Tt * Dd) / (8 * TPB)), dim3(TPB), 0, stream>>>(x, xb);
    hipLaunchCooperativeKernel((const void*)lstm_team<true>,
                               dim3(NWG), dim3(TPB), args, 0, stream);
  } else {
    hipLaunchCooperativeKernel((const void*)lstm_team<false>,
                               dim3(NWG), dim3(TPB), args, 0, stream);
  }
}

// Round 8
// 6317.650 us; speedup vs baseline: 3.0757x; 1.3336x over previous
//
#include <hip/hip_runtime.h>

typedef unsigned short u16;
typedef unsigned long long u64;
typedef __attribute__((ext_vector_type(8))) short short8;
typedef __attribute__((ext_vector_type(4))) float f32x4;

#define DEVINL __device__ __forceinline__

constexpr int Nb = 64;     // batch
constexpr int Tt = 1024;   // time
constexpr int Dd = 1024;   // input dim
constexpr int Hh = 1024;   // hidden
constexpr int NWG = 256;   // workgroups (== CUs)
constexpr int TPB = 256;   // threads per wg (4 waves)
constexpr int TWG = 128;   // wgs per team
constexpr int MS  = 32;    // samples per team

DEVINL u16 f2b(float f) {
  union { float f; unsigned u; } v; v.f = f;
  unsigned r = (v.u + 0x7fffu + ((v.u >> 16) & 1u)) >> 16;
  return (u16)r;
}
DEVINL float sigm(float x) { return 1.f / (1.f + __expf(-x)); }
DEVINL float tanhfast(float x) { float e = __expf(2.f * x); return 1.f - 2.f / (e + 1.f); }

// IC-coherent (SC1) h-fragment load (fallback path only).
DEVINL short8 ldh16(const u16* p) {
  u64 a = __hip_atomic_load((const u64*)p,       __ATOMIC_RELAXED, __HIP_MEMORY_SCOPE_AGENT);
  u64 b = __hip_atomic_load((const u64*)(p + 4), __ATOMIC_RELAXED, __HIP_MEMORY_SCOPE_AGENT);
  union { u64 q[2]; short8 v; } u;
  u.q[0] = a; u.q[1] = b;
  return u.v;
}

// Raw LDS barrier: lgkmcnt drain + s_barrier; does NOT drain vmcnt.
DEVINL void bar_w() {
  asm volatile("s_waitcnt lgkmcnt(0)" ::: "memory");
  __builtin_amdgcn_s_barrier();
}

__global__ void cvt_x_kernel(const float* __restrict__ x, u16* __restrict__ xb) {
  size_t i = ((size_t)blockIdx.x * TPB + threadIdx.x) * 8;
  float4 a = *reinterpret_cast<const float4*>(x + i);
  float4 b = *reinterpret_cast<const float4*>(x + i + 4);
  short8 r;
  r[0] = (short)f2b(a.x); r[1] = (short)f2b(a.y);
  r[2] = (short)f2b(a.z); r[3] = (short)f2b(a.w);
  r[4] = (short)f2b(b.x); r[5] = (short)f2b(b.y);
  r[6] = (short)f2b(b.z); r[7] = (short)f2b(b.w);
  *reinterpret_cast<short8*>(xb + i) = r;
}

// 2 teams x 128 wgs; team owns 32 samples, wg owns 8 h-cols.
// HIST=1: h lives in a per-step history buffer hist[t][n][j]. Producers
// publish via relaxed SC1 u64 stores (write-through to IC, no L2 copies);
// consumers read with NORMAL CACHED loads — every hist address is written
// then read exactly once per dispatch, so no L2 line can be stale; the
// first same-XCD toucher misses to IC, the rest hit L2. This removes the
// 16 MB/step SC1 broadcast (the r3-r7 ~8.5ms plateau == ~2 TB/s on the
// IC atomic path).
// Flag invariant (r6 fix): flag[r]==e guarantees h cols [8r,8r+8) of
// slot e-1 hold h_{e-1} for all 32 rows. Wave w polls wgs [32w,32w+32),
// the producers of its K-slice cols [256w,256w+256). 128B hist lines
// never cross a poll-group boundary.
template<bool XBF16, bool HIST>
__global__ __launch_bounds__(TPB, 1) void lstm_team(
    const float* __restrict__ x, const u16* __restrict__ xb,
    const float* __restrict__ h0, const float* __restrict__ Wx,
    const float* __restrict__ Wh, const float* __restrict__ bias,
    float* __restrict__ out, u16* __restrict__ hmem,
    unsigned* __restrict__ flg)
{
  __shared__ u16 Bt[32][2048];       // 128 KiB (one-time staging)
  __shared__ float ex[4][32][36];    // 18 KiB partial-sum exchange
  __shared__ u16 hstage[32][8];      // h repack for u64 stores
  __shared__ float ostage[8][8];     // wave0's f32 out handoff

  const int g   = blockIdx.x;
  const int tid = threadIdx.x;
  const int w   = tid >> 6;
  const int l   = tid & 63;

  const int team = ((g & 7) < 4) ? 0 : 1;
  const int r    = (g >> 3) * 4 + (g & 3);  // rank in team, 0..127
  const int n0   = team * MS;
  const int jc0  = r * 8;                   // this wg's 8 h-columns

  unsigned* tFlg = flg + team * 4 * 32;     // 4 packed lines of 32 epochs
  // HIST: per-team 1024 slots of MS*Hh; else depth-2 ping-pong.
  u16* hb0 = HIST ? hmem + (size_t)team * ((size_t)Tt * MS * Hh)
                  : hmem + (size_t)team * (2 * MS * Hh);

  // ---- one-time: [Wh;Wx] column slice -> LDS bf16, swizzled ----
  for (int idx = tid; idx < 32 * 2048; idx += TPB) {
    int k = idx >> 5;
    int c = idx & 31;
    int pc = (c >> 3) * 1024 + jc0 + (c & 7);
    float v = (k < 1024) ? Wh[(size_t)k * 4096 + pc]
                         : Wx[(size_t)(k - 1024) * 4096 + pc];
    Bt[c][k ^ ((c & 7) << 3)] = f2b(v);
  }

  // ---- one-time init, SAME ownership as main-loop h-stores:
  //      wg r writes columns [jc0, jc0+8) x rows 0..31 of slot 0 ----
  if (tid < 64) {
    int n  = tid >> 1;
    int jc = (tid & 1) * 4;
    const float* hp = h0 + (size_t)(n0 + n) * Hh + jc0 + jc;
    u64 pk = (u64)f2b(hp[0]) | ((u64)f2b(hp[1]) << 16) |
             ((u64)f2b(hp[2]) << 32) | ((u64)f2b(hp[3]) << 48);
    __hip_atomic_store((u64*)(hb0 + n * Hh + jc0 + jc), pk,
                       __ATOMIC_RELAXED, __HIP_MEMORY_SCOPE_AGENT);
    asm volatile("s_waitcnt vmcnt(0)" ::: "memory");
    if (tid == 0)
      __hip_atomic_store(&tFlg[r], 1u, __ATOMIC_RELAXED, __HIP_MEMORY_SCOPE_AGENT);
  }
  __syncthreads();  // Bt ready (one-time full sync)

  // epilogue roles
  const int jj = tid & 7;
  const int nE = tid >> 3;
  const float bI = bias[0 * 1024 + jc0 + jj];
  const float bF = bias[1 * 1024 + jc0 + jj];
  const float bO = bias[2 * 1024 + jc0 + jj];
  const float bG = bias[3 * 1024 + jc0 + jj];
  float c_reg = 0.f;

  // MFMA lane roles; wave owns K-slice [256w, 256w+256)
  const int arow = l & 15;
  const int kg   = (l >> 4) * 8;
  const int kb   = w * 256;
  const int sw   = (l & 7) << 3;
  const u16* bp0 = &Bt[l & 15][0];
  const u16* bp1 = &Bt[16 | (l & 15)][0];

  // ---- hoist loop-invariant B-fragments ----
  short8 bh0[8], bh1[8], bx0[8], bx1[8];
  #pragma unroll
  for (int i = 0; i < 8; ++i) {
    int ka = (kb + kg + 32 * i) ^ sw;
    bh0[i] = *reinterpret_cast<const short8*>(bp0 + ka);
    bh1[i] = *reinterpret_cast<const short8*>(bp1 + ka);
    int kx = (1024 + kb + kg + 32 * i) ^ sw;
    bx0[i] = *reinterpret_cast<const short8*>(bp0 + kx);
    bx1[i] = *reinterpret_cast<const short8*>(bp1 + kx);
  }

  for (int t = 0; t < Tt; ++t) {
    const u16* hb  = HIST ? hb0 + (size_t)t * (MS * Hh)
                          : hb0 + (t & 1) * (MS * Hh);
    u16*       hbn = HIST ? hb0 + (size_t)(t + 1) * (MS * Hh)
                          : hb0 + ((t + 1) & 1) * (MS * Hh);

    // ---- x-fragment loads BEFORE the gate (latency hides under wait) ----
    short8 xv0[8], xv1[8];
    if constexpr (XBF16) {
      const u16* xr0 = xb + ((size_t)(n0 + arow)      * Tt + t) * Dd + kb + kg;
      const u16* xr1 = xb + ((size_t)(n0 + 16 + arow) * Tt + t) * Dd + kb + kg;
      #pragma unroll
      for (int i = 0; i < 8; ++i) {
        xv0[i] = *reinterpret_cast<const short8*>(xr0 + 32 * i);
        xv1[i] = *reinterpret_cast<const short8*>(xr1 + 32 * i);
      }
    } else {
      const float* xr0 = x + ((size_t)(n0 + arow)      * Tt + t) * Dd + kb + kg;
      const float* xr1 = x + ((size_t)(n0 + 16 + arow) * Tt + t) * Dd + kb + kg;
      #pragma unroll
      for (int i = 0; i < 8; ++i) {
        float4 a0 = *reinterpret_cast<const float4*>(xr0 + 32 * i);
        float4 a1 = *reinterpret_cast<const float4*>(xr0 + 32 * i + 4);
        float4 c0 = *reinterpret_cast<const float4*>(xr1 + 32 * i);
        float4 c1 = *reinterpret_cast<const float4*>(xr1 + 32 * i + 4);
        short8 v0, v1;
        v0[0]=(short)f2b(a0.x); v0[1]=(short)f2b(a0.y);
        v0[2]=(short)f2b(a0.z); v0[3]=(short)f2b(a0.w);
        v0[4]=(short)f2b(a1.x); v0[5]=(short)f2b(a1.y);
        v0[6]=(short)f2b(a1.z); v0[7]=(short)f2b(a1.w);
        v1[0]=(short)f2b(c0.x); v1[1]=(short)f2b(c0.y);
        v1[2]=(short)f2b(c0.z); v1[3]=(short)f2b(c0.w);
        v1[4]=(short)f2b(c1.x); v1[5]=(short)f2b(c1.y);
        v1[6]=(short)f2b(c1.z); v1[7]=(short)f2b(c1.w);
        xv0[i] = v0; xv1[i] = v1;
      }
    }

    // ---- gate: poll this wave's PACKED group line (1 coalesced txn) ----
    {
      const unsigned ep = (unsigned)(t + 1);
      const unsigned* gl = tFlg + w * 32;
      bool rdy;
      do {
        unsigned f = 0xFFFFFFFFu;
        if (l < 32)
          f = __hip_atomic_load(gl + l, __ATOMIC_RELAXED, __HIP_MEMORY_SCOPE_AGENT);
        rdy = (bool)__all(f >= ep);
        if (!rdy) __builtin_amdgcn_s_sleep(1);
      } while (!rdy);
    }
    // compile-time fence: h loads below must not be hoisted above the gate
    asm volatile("" ::: "memory");

    // ---- h loads: HIST -> normal cached (fresh addr, L2-shareable);
    //      fallback -> SC1 ----
    short8 hv0[8], hv1[8];
    {
      const u16* hr = hb + (size_t)arow * Hh + kb + kg;
      #pragma unroll
      for (int i = 0; i < 8; ++i) {
        if constexpr (HIST) {
          hv0[i] = *reinterpret_cast<const short8*>(hr + 32 * i);
          hv1[i] = *reinterpret_cast<const short8*>(hr + 16 * Hh + 32 * i);
        } else {
          hv0[i] = ldh16(hr + 32 * i);
          hv1[i] = ldh16(hr + 16 * Hh + 32 * i);
        }
      }
    }

    f32x4 a00 = {0.f,0.f,0.f,0.f}, a01 = {0.f,0.f,0.f,0.f};
    f32x4 a10 = {0.f,0.f,0.f,0.f}, a11 = {0.f,0.f,0.f,0.f};

    // ---- x MFMAs (data already resident) ----
    #pragma unroll
    for (int i = 0; i < 8; ++i) {
      a00 = __builtin_amdgcn_mfma_f32_16x16x32_bf16(xv0[i], bx0[i], a00, 0, 0, 0);
      a01 = __builtin_amdgcn_mfma_f32_16x16x32_bf16(xv0[i], bx1[i], a01, 0, 0, 0);
      a10 = __builtin_amdgcn_mfma_f32_16x16x32_bf16(xv1[i], bx0[i], a10, 0, 0, 0);
      a11 = __builtin_amdgcn_mfma_f32_16x16x32_bf16(xv1[i], bx1[i], a11, 0, 0, 0);
    }
    // ---- h MFMAs ----
    #pragma unroll
    for (int i = 0; i < 8; ++i) {
      a00 = __builtin_amdgcn_mfma_f32_16x16x32_bf16(hv0[i], bh0[i], a00, 0, 0, 0);
      a01 = __builtin_amdgcn_mfma_f32_16x16x32_bf16(hv0[i], bh1[i], a01, 0, 0, 0);
      a10 = __builtin_amdgcn_mfma_f32_16x16x32_bf16(hv1[i], bh0[i], a10, 0, 0, 0);
      a11 = __builtin_amdgcn_mfma_f32_16x16x32_bf16(hv1[i], bh1[i], a11, 0, 0, 0);
    }

    // ---- partial sums -> LDS ----
    #pragma unroll
    for (int q = 0; q < 4; ++q) {
      ex[w][ 0 + (l >> 4) * 4 + q][ 0 + (l & 15)] = a00[q];
      ex[w][ 0 + (l >> 4) * 4 + q][16 + (l & 15)] = a01[q];
      ex[w][16 + (l >> 4) * 4 + q][ 0 + (l & 15)] = a10[q];
      ex[w][16 + (l >> 4) * 4 + q][16 + (l & 15)] = a11[q];
    }
    bar_w();  // SYNC1 (no vmcnt drain)

    // ---- gates, state update ----
    float pI = bI, pF = bF, pO = bO, pG = bG;
    #pragma unroll
    for (int wv = 0; wv < 4; ++wv) {
      pI += ex[wv][nE][ 0 + jj];
      pF += ex[wv][nE][ 8 + jj];
      pO += ex[wv][nE][16 + jj];
      pG += ex[wv][nE][24 + jj];
    }
    const float ig = sigm(pI), fg = sigm(pF), og = sigm(pO);
    const float gg = tanhfast(pG);
    c_reg = fg * c_reg + ig * gg;
    const float hv = og * tanhfast(c_reg);

    hstage[nE][jj] = f2b(hv);
    if (w == 0) ostage[nE][jj] = hv;   // wave0 rows 0..7 f32 handoff
    bar_w();  // SYNC2 (no vmcnt drain)

    if (tid < 64) {
      // wave0: SC1 h store -> drain (ONLY these stores) -> packed flag
      int n  = tid >> 1;
      int jc = (tid & 1) * 4;
      u64 pk = *reinterpret_cast<const u64*>(&hstage[n][jc]);
      __hip_atomic_store((u64*)(hbn + n * Hh + jc0 + jc), pk,
                         __ATOMIC_RELAXED, __HIP_MEMORY_SCOPE_AGENT);
      asm volatile("s_waitcnt vmcnt(0)" ::: "memory");
      if (tid == 0 && t + 1 < Tt)
        __hip_atomic_store(&tFlg[r], (unsigned)(t + 2),
                           __ATOMIC_RELAXED, __HIP_MEMORY_SCOPE_AGENT);
    } else {
      // waves 1-3: own out values; wave1 also stores wave0's via ostage
      out[((size_t)(n0 + nE) * Tt + t) * Hh + jc0 + jj] = hv;
      if (tid < 128) {
        int n  = (tid - 64) >> 3;
        int jo = (tid - 64) & 7;
        out[((size_t)(n0 + n) * Tt + t) * Hh + jc0 + jo] = ostage[n][jo];
      }
    }
  }
}

extern "C" void kernel_launch(void* const* d_in, const int* in_sizes, int n_in,
                              void* d_out, int out_size, void* d_ws, size_t ws_size,
                              hipStream_t stream) {
  const float* x    = (const float*)d_in[0];
  const float* h0   = (const float*)d_in[1];
  const float* Wx   = (const float*)d_in[2];
  const float* Wh   = (const float*)d_in[3];
  const float* bias = (const float*)d_in[4];
  float* out = (float*)d_out;

  char* wsb = (char*)d_ws;
  unsigned* flg = (unsigned*)wsb;                  // 2 teams x 4 x 32 u32 = 1 KiB

  const size_t hist_off   = (size_t)1 << 20;
  const size_t hist_bytes = (size_t)2 * Tt * MS * Hh * 2;       // 128 MiB
  const size_t xb_bytes   = (size_t)Nb * Tt * Dd * 2;           // 128 MiB

  const bool use_hist = ws_size >= hist_off + hist_bytes;
  const size_t xb_off = use_hist ? hist_off + hist_bytes : hist_off;
  const bool use_xb   = ws_size >= xb_off + xb_bytes;

  u16* hmem = use_hist ? (u16*)(wsb + hist_off) : (u16*)(wsb + 65536);
  u16* xb   = (u16*)(wsb + xb_off);

  hipMemsetAsync(wsb, 0, 40960, stream);           // clear flags each launch

  void* args[] = {(void*)&x, (void*)&xb, (void*)&h0, (void*)&Wx, (void*)&Wh,
                  (void*)&bias, (void*)&out, (void*)&hmem, (void*)&flg};
  if (use_xb)
    cvt_x_kernel<<<dim3((Nb * Tt * Dd) / (8 * TPB)), dim3(TPB), 0, stream>>>(x, xb);

  const void* kfn =
      use_hist ? (use_xb ? (const void*)lstm_team<true, true>
                         : (const void*)lstm_team<false, true>)
               : (use_xb ? (const void*)lstm_team<true, false>
                         : (const void*)lstm_team<false, false>);
  hipLaunchCooperativeKernel(kfn, dim3(NWG), dim3(TPB), args, 0, stream);
}